// Round 2
// baseline (1058.644 us; speedup 1.0000x reference)
//
#include <hip/hip_runtime.h>

// B=4, C=64, H=W=512, LAT=256
// ws layout (bytes):
//   [0, 4096)            sd: layer0 {s[4][64], d[4][64]}, layer1 same (fp32)
//   [4096, 593920)       wT bf16 [l][b][kk][co][ci]  (294912 shorts)
//   [593920, +128MB)     xT bf16 NHWC [b][y][x][ci]
//   [134811648, +128MB)  mid bf16 NHWC
// total 269,029,376 B

typedef __attribute__((ext_vector_type(8))) __bf16 bf16x8;
typedef __attribute__((ext_vector_type(4))) float f32x4;

typedef const __attribute__((address_space(1))) void gvoid;
typedef __attribute__((address_space(3))) void lvoid;

#define LRELU_SLOPE 0.2f
#define ACT_GAIN 1.4142135623730951f

__device__ __forceinline__ unsigned short f2bf(float f) {
    unsigned u = __builtin_bit_cast(unsigned, f);
    u += 0x7fffu + ((u >> 16) & 1u);   // RNE
    return (unsigned short)(u >> 16);
}
__device__ __forceinline__ float actvn(float v) {
    return (v >= 0.f ? v : LRELU_SLOPE * v) * ACT_GAIN;
}

__global__ __launch_bounds__(256) void prep_sd_kernel(
    const float* __restrict__ latent,
    const float* __restrict__ w0, const float* __restrict__ mw0, const float* __restrict__ mb0,
    const float* __restrict__ w1, const float* __restrict__ mw1, const float* __restrict__ mb1,
    float* __restrict__ sd)
{
    const int layer = blockIdx.x;
    const float* w  = layer ? w1  : w0;
    const float* mw = layer ? mw1 : mw0;
    const float* mb = layer ? mb1 : mb0;
    float* s_out = sd + layer * 512;
    float* d_out = s_out + 256;

    __shared__ float s_sh[256];
    __shared__ float wsq[4096];

    const int t = threadIdx.x;
    const int b = t >> 6, c = t & 63;

    {
        float acc = 0.f;
        const float* lat = latent + b * 256;
        const float* mwr = mw + c * 256;
        for (int l = 0; l < 256; ++l) acc = fmaf(lat[l], mwr[l], acc);
        float s = 1.f + acc * 0.08838834764831845f + mb[c];
        s_sh[t] = s;
        s_out[t] = s;
    }
    for (int idx = t; idx < 4096; idx += 256) {
        float a = 0.f;
        const float* wr = w + idx * 9;
        #pragma unroll
        for (int k = 0; k < 9; ++k) a = fmaf(wr[k], wr[k], a);
        wsq[idx] = a * (2.0f / 576.0f);
    }
    __syncthreads();
    {
        float a = 0.f;
        const float* sr = s_sh + b * 64;
        const float* qr = wsq + c * 64;
        for (int i = 0; i < 64; ++i) {
            float s = sr[i];
            a = fmaf(s * s, qr[i], a);
        }
        d_out[t] = rsqrtf(a + 1e-5f);
    }
}

// wT[l][b][kk][co][ci] = bf16( d*s*wscale * w[co][ci][ky][kx] )
__global__ __launch_bounds__(256) void prep_wbT_kernel(
    const float* __restrict__ w0, const float* __restrict__ w1,
    const float* __restrict__ sd, unsigned short* __restrict__ wT)
{
    int idx = blockIdx.x * 256 + threadIdx.x;   // 294912
    int l  = idx / 147456;
    int r  = idx - l * 147456;
    int b  = r / 36864;
    int r2 = r - b * 36864;                     // kk*4096 + co*64 + ci
    int ci = r2 & 63, co = (r2 >> 6) & 63, kk = r2 >> 12;
    const float* w   = l ? w1 : w0;
    const float* sdl = sd + l * 512;
    float v = sdl[b * 64 + ci] * sdl[256 + b * 64 + co] * 0.05892556509887896f
            * w[(co * 64 + ci) * 9 + kk];
    wT[idx] = f2bf(v);
}

// NCHW fp32 -> NHWC bf16. 256 px x 64 ci per block; 64 independent loads/thread.
__global__ __launch_bounds__(256) void transpose_kernel(
    const float* __restrict__ x, unsigned short* __restrict__ xT)
{
    __shared__ unsigned short tl[256 * 72];     // 36,864 B
    const int b = blockIdx.y;
    const size_t pxbase = (size_t)blockIdx.x * 256;
    const int t = threadIdx.x, l = t & 63, w = t >> 6;
    const float* src = x + (size_t)b * 64 * 262144;
    #pragma unroll
    for (int i = 0; i < 16; ++i) {
        int ci = w * 16 + i;
        #pragma unroll
        for (int j = 0; j < 4; ++j) {
            int px = j * 64 + l;
            float v = src[(size_t)ci * 262144 + pxbase + px];
            tl[px * 72 + ci] = f2bf(v);
        }
    }
    __syncthreads();
    unsigned short* dst = xT + ((size_t)b * 262144 + pxbase) * 64;
    #pragma unroll
    for (int j = 0; j < 8; ++j) {
        int idx = t + j * 256;          // 2048 chunks: 256 px x 8
        int p2 = idx >> 3, c8 = idx & 7;
        *(uint4*)&dst[(size_t)p2 * 64 + c8 * 8] = *(const uint4*)&tl[p2 * 72 + c8 * 8];
    }
}

// Persistent-strip implicit-GEMM 3x3 conv, reflect pad, bf16 MFMA 16x16x32.
// Block: 16-px-wide column strip, 16 y-tiles of 16 rows. Double-buffered LDS,
// async global_load_lds staging of tile t+1 issued before compute of tile t.
// Weights register-resident (72 x bf16x8 per thread). grid (32, 2, 4) = 256 blocks.
// LDS buffer: linear [324 px][64 ci], 16B chunk XOR-swizzled: slot = chunk ^ (px&7)
// (swizzle applied on pre-swizzled GLOBAL source address; read applies same XOR).
template<int OUT_NCHW>
__global__ __launch_bounds__(256, 1) void conv_mfma_kernel(
    const unsigned short* __restrict__ inT,   // [b][y][x][ci] bf16
    const unsigned short* __restrict__ wT,    // [b][kk][co][ci] bf16 (layer slice)
    const float* __restrict__ bias,
    void* __restrict__ outp)
{
    __shared__ unsigned short lds[2][20736];  // 2 x 41,472 B
    const int x0 = blockIdx.x * 16;
    const int ystart = blockIdx.y * 256;
    const int b = blockIdx.z;
    const int t = threadIdx.x, wave = t >> 6, lane = t & 63;
    const int col = lane & 15, hi = lane >> 4;
    const int r0 = wave * 4;

    const unsigned short* src = inT + (size_t)b * (512 * 512 * 64);

    // ---- weights -> registers (once per block) ----
    const unsigned short* wb = wT + (size_t)b * (9 * 4096);
    bf16x8 bw[9][2][4];
    #pragma unroll
    for (int kk = 0; kk < 9; ++kk)
        #pragma unroll
        for (int kc = 0; kc < 2; ++kc)
            #pragma unroll
            for (int n = 0; n < 4; ++n)
                bw[kk][kc][n] = *(const bf16x8*)&wb[kk * 4096 + (n * 16 + col) * 64 + kc * 32 + hi * 8];

    float bv[4];
    #pragma unroll
    for (int n = 0; n < 4; ++n) bv[n] = bias[n * 16 + col];

    // ---- async stage one 18x18 halo tile into buf (linear dest, swizzled src) ----
    auto STAGE = [&](unsigned short* buf, int ty0) {
        #pragma unroll
        for (int j = 0; j < 11; ++j) {
            int ch = j * 256 + wave * 64 + lane;      // chunk id, 2592 total
            if (ch < 2592) {
                int p = ch >> 3, s = ch & 7;          // pixel, lds slot
                int pr = p / 18, pc = p - pr * 18;
                int gy = ty0 + pr - 1; gy = gy < 0 ? 1 : (gy > 511 ? 510 : gy);
                int gx = x0 + pc - 1;  gx = gx < 0 ? 1 : (gx > 511 ? 510 : gx);
                int c = s ^ (p & 7);                  // which ci-chunk lives in slot s
                const unsigned short* g = src + (((size_t)(gy * 512 + gx)) << 6) + (c << 3);
                unsigned short* ld = buf + (size_t)(j * 256 + wave * 64) * 8;  // wave-uniform
                __builtin_amdgcn_global_load_lds((gvoid*)g, (lvoid*)ld, 16, 0, 0);
            }
        }
    };

    unsigned short* bufc = &lds[0][0];
    unsigned short* bufn = &lds[1][0];

    STAGE(bufc, ystart);          // tile 0
    __syncthreads();              // vmcnt(0) drain + barrier

    for (int tt = 0; tt < 16; ++tt) {
        const int ty0 = ystart + tt * 16;
        if (tt < 15) STAGE(bufn, ty0 + 16);   // issue next-tile loads (stay in flight)

        f32x4 acc[4][4];
        #pragma unroll
        for (int m = 0; m < 4; ++m)
            #pragma unroll
            for (int n = 0; n < 4; ++n) acc[m][n] = (f32x4)(0.f);

        #pragma unroll
        for (int kk = 0; kk < 9; ++kk) {
            const int ky = kk / 3, kx = kk - ky * 3;
            #pragma unroll
            for (int kc = 0; kc < 2; ++kc) {
                #pragma unroll
                for (int m = 0; m < 4; ++m) {
                    int p = (r0 + m + ky) * 18 + col + kx;
                    int sl = (kc * 4 + hi) ^ (p & 7);
                    bf16x8 a = *(const bf16x8*)&bufc[p * 64 + sl * 8];
                    #pragma unroll
                    for (int n = 0; n < 4; ++n)
                        acc[m][n] = __builtin_amdgcn_mfma_f32_16x16x32_bf16(a, bw[kk][kc][n], acc[m][n], 0, 0, 0);
                }
            }
        }

        if (OUT_NCHW) {
            // D layout: m = y row, x = hi*4+reg, co = n*16+col -> float4 along x
            float* out = (float*)outp;
            #pragma unroll
            for (int mt = 0; mt < 4; ++mt) {
                int gy = ty0 + r0 + mt;
                #pragma unroll
                for (int n = 0; n < 4; ++n) {
                    int co = n * 16 + col;
                    float4 v;
                    v.x = actvn(acc[mt][n][0] + bv[n]);
                    v.y = actvn(acc[mt][n][1] + bv[n]);
                    v.z = actvn(acc[mt][n][2] + bv[n]);
                    v.w = actvn(acc[mt][n][3] + bv[n]);
                    *(float4*)&out[((size_t)(b * 64 + co) * 512 + gy) * 512 + x0 + hi * 4] = v;
                }
            }
            __syncthreads();   // all waves done with bufc; bufn loads drained
        } else {
            // NHWC bf16 out: reuse just-consumed bufc as transpose scratch
            unsigned short* out = (unsigned short*)outp;
            __syncthreads();                         // all waves done reading bufc
            unsigned short* sw = bufc + wave * 4608; // 64 px x 72
            #pragma unroll
            for (int mt = 0; mt < 4; ++mt)
                #pragma unroll
                for (int n = 0; n < 4; ++n) {
                    int co = n * 16 + col;
                    #pragma unroll
                    for (int rg = 0; rg < 4; ++rg) {
                        int px = mt * 16 + hi * 4 + rg;
                        sw[px * 72 + co] = f2bf(actvn(acc[mt][n][rg] + bv[n]));
                    }
                }
            #pragma unroll
            for (int j = 0; j < 4; ++j) {
                int idx = lane + j * 64;             // 256 chunks: 32... (64 px x 8) per wave
                int px = idx >> 3, c8 = idx & 7;
                int gy = ty0 + r0 + (px >> 4), gx = x0 + (px & 15);
                *(uint4*)&out[((size_t)b * 262144 + gy * 512 + gx) * 64 + c8 * 8] =
                    *(const uint4*)&sw[px * 72 + c8 * 8];
            }
            #pragma unroll
            for (int j = 4; j < 8; ++j) {
                int idx = lane + j * 64;
                int px = idx >> 3, c8 = idx & 7;
                int gy = ty0 + r0 + (px >> 4), gx = x0 + (px & 15);
                *(uint4*)&out[((size_t)b * 262144 + gy * 512 + gx) * 64 + c8 * 8] =
                    *(const uint4*)&sw[px * 72 + c8 * 8];
            }
            __syncthreads();   // scratch reads done; bufn loads drained
        }

        unsigned short* tmp = bufc; bufc = bufn; bufn = tmp;
    }
}

extern "C" void kernel_launch(void* const* d_in, const int* in_sizes, int n_in,
                              void* d_out, int out_size, void* d_ws, size_t ws_size,
                              hipStream_t stream) {
    const float* x      = (const float*)d_in[0];
    const float* latent = (const float*)d_in[1];
    const float* w0     = (const float*)d_in[2];
    const float* b0     = (const float*)d_in[3];
    const float* mw0    = (const float*)d_in[4];
    const float* mb0    = (const float*)d_in[5];
    const float* w1     = (const float*)d_in[6];
    const float* b1     = (const float*)d_in[7];
    const float* mw1    = (const float*)d_in[8];
    const float* mb1    = (const float*)d_in[9];

    char* wsb = (char*)d_ws;
    float* sd            = (float*)wsb;                          // 4 KB
    unsigned short* wT   = (unsigned short*)(wsb + 4096);        // 576 KB
    unsigned short* xT   = (unsigned short*)(wsb + 593920);      // 128 MB
    unsigned short* mid  = (unsigned short*)(wsb + 593920 + 134217728);

    prep_sd_kernel<<<2, 256, 0, stream>>>(latent, w0, mw0, mb0, w1, mw1, mb1, sd);
    prep_wbT_kernel<<<1152, 256, 0, stream>>>(w0, w1, sd, wT);
    transpose_kernel<<<dim3(1024, 4), 256, 0, stream>>>(x, xT);

    dim3 grid(32, 2, 4);
    conv_mfma_kernel<0><<<grid, 256, 0, stream>>>(xT, wT, b0, (void*)mid);
    conv_mfma_kernel<1><<<grid, 256, 0, stream>>>(mid, wT + 147456, b1, d_out);
}

// Round 3
// 839.109 us; speedup vs baseline: 1.2616x; 1.2616x over previous
//
#include <hip/hip_runtime.h>

// B=4, C=64, H=W=512, LAT=256
// ws layout (bytes):
//   [0, 4096)            sd: layer0 {s[4][64], d[4][64]}, layer1 same (fp32)
//   [4096, 593920)       wT bf16 [l][b][kk][co][ci]  (294912 shorts)
//   [593920, +128MB)     xT bf16 NHWC [b][y][x][ci]
//   [134811648, +128MB)  mid bf16 NHWC
// total 269,029,376 B

typedef __attribute__((ext_vector_type(8))) __bf16 bf16x8;
typedef __attribute__((ext_vector_type(4))) float f32x4;

typedef const __attribute__((address_space(1))) void gvoid;
typedef __attribute__((address_space(3))) void lvoid;

#define LRELU_SLOPE 0.2f
#define ACT_GAIN 1.4142135623730951f

__device__ __forceinline__ unsigned short f2bf(float f) {
    unsigned u = __builtin_bit_cast(unsigned, f);
    u += 0x7fffu + ((u >> 16) & 1u);   // RNE
    return (unsigned short)(u >> 16);
}
__device__ __forceinline__ float actvn(float v) {
    return (v >= 0.f ? v : LRELU_SLOPE * v) * ACT_GAIN;
}

__global__ __launch_bounds__(256) void prep_sd_kernel(
    const float* __restrict__ latent,
    const float* __restrict__ w0, const float* __restrict__ mw0, const float* __restrict__ mb0,
    const float* __restrict__ w1, const float* __restrict__ mw1, const float* __restrict__ mb1,
    float* __restrict__ sd)
{
    const int layer = blockIdx.x;
    const float* w  = layer ? w1  : w0;
    const float* mw = layer ? mw1 : mw0;
    const float* mb = layer ? mb1 : mb0;
    float* s_out = sd + layer * 512;
    float* d_out = s_out + 256;

    __shared__ float s_sh[256];
    __shared__ float wsq[4096];

    const int t = threadIdx.x;
    const int b = t >> 6, c = t & 63;

    {
        float acc = 0.f;
        const float* lat = latent + b * 256;
        const float* mwr = mw + c * 256;
        for (int l = 0; l < 256; ++l) acc = fmaf(lat[l], mwr[l], acc);
        float s = 1.f + acc * 0.08838834764831845f + mb[c];
        s_sh[t] = s;
        s_out[t] = s;
    }
    for (int idx = t; idx < 4096; idx += 256) {
        float a = 0.f;
        const float* wr = w + idx * 9;
        #pragma unroll
        for (int k = 0; k < 9; ++k) a = fmaf(wr[k], wr[k], a);
        wsq[idx] = a * (2.0f / 576.0f);
    }
    __syncthreads();
    {
        float a = 0.f;
        const float* sr = s_sh + b * 64;
        const float* qr = wsq + c * 64;
        for (int i = 0; i < 64; ++i) {
            float s = sr[i];
            a = fmaf(s * s, qr[i], a);
        }
        d_out[t] = rsqrtf(a + 1e-5f);
    }
}

// wT[l][b][kk][co][ci] = bf16( d*s*wscale * w[co][ci][ky][kx] )
__global__ __launch_bounds__(256) void prep_wbT_kernel(
    const float* __restrict__ w0, const float* __restrict__ w1,
    const float* __restrict__ sd, unsigned short* __restrict__ wT)
{
    int idx = blockIdx.x * 256 + threadIdx.x;   // 294912
    int l  = idx / 147456;
    int r  = idx - l * 147456;
    int b  = r / 36864;
    int r2 = r - b * 36864;                     // kk*4096 + co*64 + ci
    int ci = r2 & 63, co = (r2 >> 6) & 63, kk = r2 >> 12;
    const float* w   = l ? w1 : w0;
    const float* sdl = sd + l * 512;
    float v = sdl[b * 64 + ci] * sdl[256 + b * 64 + co] * 0.05892556509887896f
            * w[(co * 64 + ci) * 9 + kk];
    wT[idx] = f2bf(v);
}

// NCHW fp32 -> NHWC bf16. 256 px x 64 ci per block.
// float4 reads (16B/lane). LDS: [256 px][80 shorts], ci-group (8-ci = 16B)
// XOR-swizzled by (px>>2)&7 to break the px-stride bank alias on writes.
__global__ __launch_bounds__(256) void transpose_kernel(
    const float* __restrict__ x, unsigned short* __restrict__ xT)
{
    __shared__ unsigned short tl[256 * 80];     // 40,960 B
    const int b = blockIdx.y;
    const size_t pxbase = (size_t)blockIdx.x * 256;
    const int t = threadIdx.x, l = t & 63, w = t >> 6;
    const float* src = x + (size_t)b * 64 * 262144 + pxbase;
    const int xg = (l & 7) << 3;                // XOR key = (px>>2)&7, px = l*4+j
    #pragma unroll
    for (int i = 0; i < 8; ++i) {
        int ci0 = w * 16 + i * 2;
        float4 va = *(const float4*)&src[(size_t)ci0 * 262144 + l * 4];
        float4 vb = *(const float4*)&src[(size_t)(ci0 + 1) * 262144 + l * 4];
        const float* pa = (const float*)&va;
        const float* pb = (const float*)&vb;
        int cis = ci0 ^ xg;                     // xg multiple of 8: pair offset kept
        #pragma unroll
        for (int j = 0; j < 4; ++j) {
            int px = l * 4 + j;
            unsigned u = (unsigned)f2bf(pa[j]) | ((unsigned)f2bf(pb[j]) << 16);
            *(unsigned*)&tl[px * 80 + cis] = u;
        }
    }
    __syncthreads();
    unsigned short* dst = xT + ((size_t)b * 262144 + pxbase) * 64;
    #pragma unroll
    for (int j = 0; j < 8; ++j) {
        int idx = t + j * 256;          // 2048 chunks: 256 px x 8
        int p2 = idx >> 3, c8 = idx & 7;
        int slot = c8 ^ ((p2 >> 2) & 7);
        *(uint4*)&dst[(size_t)p2 * 64 + c8 * 8] = *(const uint4*)&tl[p2 * 80 + slot * 8];
    }
}

// Persistent-strip implicit-GEMM 3x3 conv, reflect pad, bf16 MFMA 16x16x32.
// Block: 16-px-wide strip, 16 y-tiles of 8 rows. grid (32, 4, 4) = 512 = 2 blocks/CU.
// 4 waves = 2 y-halves (wy: 4 rows each) x 2 co-halves (wn: 32 co each).
// Weights register-resident per co-half: 9kk x 2kc x 2ng = 36 x bf16x8 = 144 VGPR.
// A-reads row-structured: 6 rows x 3kx x 2kc = 36 ds_read_b128/wave/tile (vs 72 naive).
// Double-buffered 10x18x64 tiles staged via global_load_lds (16B), XOR chunk swizzle.
// One barrier per tile; next-tile loads stay in flight across compute.
template<int OUT_NCHW>
__global__ __launch_bounds__(256, 2) void conv_mfma_kernel(
    const unsigned short* __restrict__ inT,   // [b][y][x][ci] bf16
    const unsigned short* __restrict__ wT,    // [b][kk][co][ci] bf16 (layer slice)
    const float* __restrict__ bias,
    void* __restrict__ outp)
{
    __shared__ unsigned short lds[2][11520];      // 2 x 23,040 B (10 rows x 18 px x 64 ci)
    __shared__ unsigned short scratch[4][2560];   // 4 x 5,120 B  (64 px x 40, NHWC out)
    const int x0 = blockIdx.x * 16;
    const int ystart = blockIdx.y * 128;
    const int b = blockIdx.z;
    const int t = threadIdx.x, wave = t >> 6, lane = t & 63;
    const int col = lane & 15, hi = lane >> 4;
    const int wy = wave & 1, wn = wave >> 1;
    const int wy4 = wy * 4;

    const unsigned short* src = inT + (size_t)b * (512 * 512 * 64);

    // ---- weights -> registers (once per block, co-half wn) ----
    const unsigned short* wb = wT + (size_t)b * (9 * 4096);
    bf16x8 bw[9][2][2];
    #pragma unroll
    for (int kk = 0; kk < 9; ++kk)
        #pragma unroll
        for (int kc = 0; kc < 2; ++kc)
            #pragma unroll
            for (int ng = 0; ng < 2; ++ng)
                bw[kk][kc][ng] = *(const bf16x8*)&wb[kk * 4096
                    + (wn * 32 + ng * 16 + col) * 64 + kc * 32 + hi * 8];

    float bv[2];
    #pragma unroll
    for (int ng = 0; ng < 2; ++ng) bv[ng] = bias[wn * 32 + ng * 16 + col];

    // ---- async stage one 10x18 halo tile (linear LDS dest, swizzled global src) ----
    auto STAGE = [&](unsigned short* buf, int ty0) {
        #pragma unroll
        for (int j = 0; j < 6; ++j) {
            int ch = j * 256 + t;                 // chunk id, 1440 total
            if (ch < 1440) {
                int p = ch >> 3, s = ch & 7;      // pixel, lds slot
                int pr = p / 18, pc = p - pr * 18;
                int gy = ty0 + pr - 1; gy = gy < 0 ? 1 : (gy > 511 ? 510 : gy);
                int gx = x0 + pc - 1;  gx = gx < 0 ? 1 : (gx > 511 ? 510 : gx);
                int c = s ^ (p & 7);              // which ci-chunk lives in slot s
                const unsigned short* g = src + (((size_t)(gy * 512 + gx)) << 6) + (c << 3);
                unsigned short* ld = buf + (size_t)(j * 256 + wave * 64) * 8;  // wave-uniform
                __builtin_amdgcn_global_load_lds((gvoid*)g, (lvoid*)ld, 16, 0, 0);
            }
        }
    };

    unsigned short* bufc = &lds[0][0];
    unsigned short* bufn = &lds[1][0];

    STAGE(bufc, ystart);          // tile 0
    __syncthreads();              // vmcnt(0) drain + barrier

    for (int tt = 0; tt < 16; ++tt) {
        const int ty0 = ystart + tt * 8;
        if (tt < 15) STAGE(bufn, ty0 + 8);    // issue next-tile loads (stay in flight)

        f32x4 acc[4][2];
        #pragma unroll
        for (int m = 0; m < 4; ++m)
            #pragma unroll
            for (int ng = 0; ng < 2; ++ng) acc[m][ng] = (f32x4)(0.f);

        // row-structured: load each input row's 6 fragments once, feed all ky
        #pragma unroll
        for (int ir = 0; ir < 6; ++ir) {
            const int p_row = wy4 + ir;
            bf16x8 a[3][2];
            #pragma unroll
            for (int kx = 0; kx < 3; ++kx)
                #pragma unroll
                for (int kc = 0; kc < 2; ++kc) {
                    int p = p_row * 18 + col + kx;
                    int sl = (kc * 4 + hi) ^ (p & 7);
                    a[kx][kc] = *(const bf16x8*)&bufc[p * 64 + sl * 8];
                }
            #pragma unroll
            for (int ky = 0; ky < 3; ++ky) {
                const int m = ir - ky;
                if (m >= 0 && m < 4) {
                    #pragma unroll
                    for (int kx = 0; kx < 3; ++kx)
                        #pragma unroll
                        for (int kc = 0; kc < 2; ++kc)
                            #pragma unroll
                            for (int ng = 0; ng < 2; ++ng)
                                acc[m][ng] = __builtin_amdgcn_mfma_f32_16x16x32_bf16(
                                    a[kx][kc], bw[ky * 3 + kx][kc][ng], acc[m][ng], 0, 0, 0);
                }
            }
        }

        if (OUT_NCHW) {
            // D layout: x = hi*4+reg, co = wn*32 + ng*16 + col -> float4 along x
            float* out = (float*)outp;
            #pragma unroll
            for (int mt = 0; mt < 4; ++mt) {
                int gy = ty0 + wy4 + mt;
                #pragma unroll
                for (int ng = 0; ng < 2; ++ng) {
                    int co = wn * 32 + ng * 16 + col;
                    float4 v;
                    v.x = actvn(acc[mt][ng][0] + bv[ng]);
                    v.y = actvn(acc[mt][ng][1] + bv[ng]);
                    v.z = actvn(acc[mt][ng][2] + bv[ng]);
                    v.w = actvn(acc[mt][ng][3] + bv[ng]);
                    *(float4*)&out[((size_t)(b * 64 + co) * 512 + gy) * 512 + x0 + hi * 4] = v;
                }
            }
        } else {
            // NHWC bf16 out via per-wave dedicated scratch (no extra barrier)
            unsigned short* out = (unsigned short*)outp;
            unsigned short* sw = scratch[wave];     // [64 px][40] (px = m*16 + x)
            #pragma unroll
            for (int mt = 0; mt < 4; ++mt)
                #pragma unroll
                for (int ng = 0; ng < 2; ++ng) {
                    int cl = ng * 16 + col;         // co within half
                    #pragma unroll
                    for (int rg = 0; rg < 4; ++rg) {
                        int px = mt * 16 + hi * 4 + rg;
                        sw[px * 40 + cl] = f2bf(actvn(acc[mt][ng][rg] + bv[ng]));
                    }
                }
            #pragma unroll
            for (int j = 0; j < 4; ++j) {
                int idx = lane + j * 64;            // 256 chunks: 64 px x 4 (8-co)
                int px = idx >> 2, cq = idx & 3;
                int gy = ty0 + wy4 + (px >> 4), gx = x0 + (px & 15);
                *(uint4*)&out[((size_t)b * 262144 + gy * 512 + gx) * 64 + wn * 32 + cq * 8] =
                    *(const uint4*)&sw[px * 40 + cq * 8];
            }
        }

        __syncthreads();   // bufc reads done everywhere; bufn stage drained
        unsigned short* tmp = bufc; bufc = bufn; bufn = tmp;
    }
}

extern "C" void kernel_launch(void* const* d_in, const int* in_sizes, int n_in,
                              void* d_out, int out_size, void* d_ws, size_t ws_size,
                              hipStream_t stream) {
    const float* x      = (const float*)d_in[0];
    const float* latent = (const float*)d_in[1];
    const float* w0     = (const float*)d_in[2];
    const float* b0     = (const float*)d_in[3];
    const float* mw0    = (const float*)d_in[4];
    const float* mb0    = (const float*)d_in[5];
    const float* w1     = (const float*)d_in[6];
    const float* b1     = (const float*)d_in[7];
    const float* mw1    = (const float*)d_in[8];
    const float* mb1    = (const float*)d_in[9];

    char* wsb = (char*)d_ws;
    float* sd            = (float*)wsb;                          // 4 KB
    unsigned short* wT   = (unsigned short*)(wsb + 4096);        // 576 KB
    unsigned short* xT   = (unsigned short*)(wsb + 593920);      // 128 MB
    unsigned short* mid  = (unsigned short*)(wsb + 593920 + 134217728);

    prep_sd_kernel<<<2, 256, 0, stream>>>(latent, w0, mw0, mb0, w1, mw1, mb1, sd);
    prep_wbT_kernel<<<1152, 256, 0, stream>>>(w0, w1, sd, wT);
    transpose_kernel<<<dim3(1024, 4), 256, 0, stream>>>(x, xT);

    dim3 grid(32, 4, 4);
    conv_mfma_kernel<0><<<grid, 256, 0, stream>>>(xT, wT, b0, (void*)mid);
    conv_mfma_kernel<1><<<grid, 256, 0, stream>>>(mid, wT + 147456, b1, d_out);
}